// Round 14
// baseline (591.963 us; speedup 1.0000x reference)
//
#include <hip/hip_runtime.h>
#include <math.h>

#define B_DIM 512
#define WS_DIM 128
#define I_DIM 256
#define H_DIM 512
#define NWS 64
#define PRE 24
#define SEQ0 (NWS - PRE)  // 40

typedef __attribute__((ext_vector_type(8))) short short8;
typedef __attribute__((ext_vector_type(4))) float f32x4;

#define MFMA16(a, b, c) __builtin_amdgcn_mfma_f32_16x16x32_bf16((a), (b), (c), 0, 0, 0)

__device__ __forceinline__ unsigned short f2bf(float f) {
    unsigned u = __float_as_uint(f);
    u += 0x7FFF + ((u >> 16) & 1);
    return (unsigned short)(u >> 16);
}
__device__ __forceinline__ float bf2f(unsigned short h) {
    return __uint_as_float(((unsigned)h) << 16);
}

// Device-coherent (MALL) accesses: bypass the non-coherent per-XCD L2s.
__device__ __forceinline__ unsigned ld_dev(const unsigned* p) {
    return __hip_atomic_load((unsigned*)p, __ATOMIC_RELAXED, __HIP_MEMORY_SCOPE_AGENT);
}
__device__ __forceinline__ unsigned long long ld_dev64(const unsigned long long* p) {
    return __hip_atomic_load((unsigned long long*)p, __ATOMIC_RELAXED, __HIP_MEMORY_SCOPE_AGENT);
}
__device__ __forceinline__ void st_dev(unsigned* p, unsigned v) {
    __hip_atomic_store(p, v, __ATOMIC_RELAXED, __HIP_MEMORY_SCOPE_AGENT);
}

// ---------------------------------------------------------------------------
// K1: fc1 over the time axis -> y bf16. (round-13 version, proven)
// ---------------------------------------------------------------------------
__global__ void __launch_bounds__(256) fc1_kernel(const float* __restrict__ x,
                                                  const float* __restrict__ fc1_w,
                                                  const float* __restrict__ fc1_b,
                                                  unsigned short* __restrict__ y) {
    __shared__ float wsm[NWS * WS_DIM];  // 64*128 f32 = 32KB
    const int b = blockIdx.x;
    const int i = threadIdx.x;  // 0..255 == I_DIM

    for (int idx = i; idx < NWS * WS_DIM; idx += 256) wsm[idx] = fc1_w[idx];
    __syncthreads();

    float acc[NWS];
#pragma unroll
    for (int n = 0; n < NWS; ++n) acc[n] = fc1_b[n];

    const float* xb = x + (size_t)b * WS_DIM * I_DIM + i;
    for (int t = 0; t < WS_DIM; ++t) {
        float xv = xb[(size_t)t * I_DIM];
#pragma unroll
        for (int n = 0; n < NWS; ++n) acc[n] += xv * wsm[n * WS_DIM + t];
    }

    unsigned short* yb = y + (size_t)b * NWS * I_DIM + i;
#pragma unroll
    for (int n = 0; n < NWS; ++n) yb[(size_t)n * I_DIM] = f2bf(acc[n]);
}

// ---------------------------------------------------------------------------
// Persistent GRU recurrence — round-8 compute body, NORMAL LAUNCH (not
// cooperative; 256 blocks @ 1/CU on 256 CUs => co-resident in practice).
// Sync: per-block flag word, uncontended atomicAdd publish (full drain +
// barrier first), 16-lane parallel poll + barrier on the wait side.
// ---------------------------------------------------------------------------
#define LDSB (24 * 96 * 64)  // 147456 bytes

__global__ void __launch_bounds__(256, 1)
gru_persist(const unsigned short* __restrict__ y,  // [B,NWS,I] bf16
            const float* __restrict__ Wih, const float* __restrict__ bih,
            const float* __restrict__ Whh, const float* __restrict__ bhh,
            unsigned short* __restrict__ hA,   // ping [B,H] bf16 (pre-zeroed)
            unsigned short* __restrict__ hB,   // pong
            unsigned short* __restrict__ hseq, // [B,PRE,H] bf16
            unsigned* __restrict__ flags) {    // [16][NWS][16] (pre-zeroed)
    extern __shared__ char lds[];
    const int tid = threadIdx.x;
    const int lane = tid & 63;
    const int w = tid >> 6;
    const int wm = w & 1;
    const int jh = w >> 1;
    const int bt = blockIdx.x & 15;
    const int jt = blockIdx.x >> 4;
    const int b0 = bt * 32;
    const int j0 = jt * 32;

    // ---- one-time weight preload into swizzled LDS (round-3 verbatim) ----
    for (int idx = tid; idx < 96 * 768; idx += 256) {
        int n = idx / 768, k = idx % 768;
        int g = n >> 5, jj = n & 31;
        int srow = g * H_DIM + j0 + jj;
        float wv = (k < I_DIM) ? Wih[(size_t)srow * I_DIM + k]
                               : Whh[(size_t)srow * H_DIM + (k - I_DIM)];
        int ks = k >> 5, q = (k & 31) >> 3, e = k & 7;
        int byteoff = ks * 6144 + (((n * 64 + q * 16) ^ ((n & 7) << 4)) + e * 2);
        *(unsigned short*)(lds + byteoff) = f2bf(wv);
    }

    const int row16 = lane & 15;
    const int qg = lane >> 4;
    const int bbA = b0 + wm * 16 + row16;  // A-fragment source row
    const int jj = jh * 16 + row16;        // C col within 32-j slice
    const int j = j0 + jj;

    const int n0r = jj, n1r = 32 + jj, n2r = 64 + jj;
    const int bof0 = (n0r * 64 + qg * 16) ^ ((n0r & 7) << 4);
    const int bof1 = (n1r * 64 + qg * 16) ^ ((n1r & 7) << 4);
    const int bof2 = (n2r * 64 + qg * 16) ^ ((n2r & 7) << 4);

    const float br_i = bih[j], br_h = bhh[j];
    const float bz_i = bih[H_DIM + j], bz_h = bhh[H_DIM + j];
    const float bn_i = bih[2 * H_DIM + j], bn_h = bhh[2 * H_DIM + j];

    __syncthreads();  // LDS weights ready (one-time)

    const unsigned short* ybase = y + (size_t)bbA * NWS * I_DIM + qg * 8;

    short8 yf0[8], yf1[8];
#pragma unroll
    for (int ks = 0; ks < 8; ++ks) yf0[ks] = *(const short8*)(ybase + ks * 32);

    auto STEP = [&](int step, short8(&yc)[8], short8(&yn)[8]) {
        const unsigned short* hin = (step & 1) ? hB : hA;
        unsigned short* hout      = (step & 1) ? hA : hB;

        f32x4 aR = {br_i, br_i, br_i, br_i};
        f32x4 aZ = {bz_i, bz_i, bz_i, bz_i};
        f32x4 aN = {bn_i, bn_i, bn_i, bn_i};

        // ---- input phase (no h dependency) ----
#pragma unroll
        for (int ks = 0; ks < 8; ++ks) {
            short8 bf0 = *(const short8*)(lds + ks * 6144 + bof0);
            short8 bf1 = *(const short8*)(lds + ks * 6144 + bof1);
            short8 bf2 = *(const short8*)(lds + ks * 6144 + bof2);
            aR = MFMA16(yc[ks], bf0, aR);
            aZ = MFMA16(yc[ks], bf1, aZ);
            aN = MFMA16(yc[ks], bf2, aN);
        }

        // ---- prefetch next step's y fragments (overlaps the wait) ----
        int sn = (step + 1 < NWS) ? step + 1 : NWS - 1;
        const unsigned short* ypn = ybase + (size_t)sn * I_DIM;
#pragma unroll
        for (int ks = 0; ks < 8; ++ks) yn[ks] = *(const short8*)(ypn + ks * 32);

        // ---- wait: 16 per-block flag words for step-1, polled in parallel ----
        if (step > 0) {
            const unsigned* dw = flags + ((size_t)bt * NWS + (step - 1)) * 16;
            while (true) {
                unsigned v = ld_dev(dw + (lane & 15));
                if (__all(v != 0)) break;
                __builtin_amdgcn_s_sleep(1);
            }
            asm volatile("" ::: "memory");
            __syncthreads();
        }

        // ---- h fragment loads (MALL-coherent) ----
        const unsigned long long* hq = (const unsigned long long*)(hin + (size_t)bbA * H_DIM);
        short8 hf[16];
#pragma unroll
        for (int ks = 0; ks < 16; ++ks) {
            union { unsigned long long u[2]; short8 s; } t;
            t.u[0] = ld_dev64(hq + ks * 8 + qg * 2);
            t.u[1] = ld_dev64(hq + ks * 8 + qg * 2 + 1);
            hf[ks] = t.s;
        }
        // hprev for the epilogue (overlaps MFMA below)
        unsigned hw[4];
        const unsigned* h32 = (const unsigned*)hin;
#pragma unroll
        for (int r = 0; r < 4; ++r) {
            int brow = b0 + wm * 16 + qg * 4 + r;
            hw[r] = ld_dev(h32 + brow * (H_DIM / 2) + (j >> 1));
        }

        // ---- hidden phase: B-operands from LDS ----
        f32x4 hR = {br_h, br_h, br_h, br_h};
        f32x4 hZ = {bz_h, bz_h, bz_h, bz_h};
        f32x4 hN = {bn_h, bn_h, bn_h, bn_h};
#pragma unroll
        for (int ks = 0; ks < 16; ++ks) {
            short8 bf0 = *(const short8*)(lds + (8 + ks) * 6144 + bof0);
            short8 bf1 = *(const short8*)(lds + (8 + ks) * 6144 + bof1);
            short8 bf2 = *(const short8*)(lds + (8 + ks) * 6144 + bof2);
            hR = MFMA16(hf[ks], bf0, hR);
            hZ = MFMA16(hf[ks], bf1, hZ);
            hN = MFMA16(hf[ks], bf2, hN);
        }

        // ---- epilogue: gating; C/D layout col=lane&15, row=qg*4+r ----
        unsigned short hbf[4];
#pragma unroll
        for (int r = 0; r < 4; ++r) {
            int brow = b0 + wm * 16 + qg * 4 + r;
            float pr = aR[r] + hR[r];
            float pz = aZ[r] + hZ[r];
            float rr = 1.f / (1.f + __expf(-pr));
            float zz = 1.f / (1.f + __expf(-pz));
            float pn = aN[r] + rr * hN[r];
            float ax = fabsf(pn);
            float e2 = __expf(2.f * ax);
            float nn = copysignf(1.f - 2.f / (e2 + 1.f), pn);
            float hprev = bf2f((unsigned short)((j & 1) ? (hw[r] >> 16) : (hw[r] & 0xffff)));
            float hnew = (1.f - zz) * nn + zz * hprev;
            hbf[r] = f2bf(hnew);
            unsigned v = hbf[r];
            unsigned o = __shfl_xor(v, 1);
            if (!(lane & 1))
                st_dev((unsigned*)hout + brow * (H_DIM / 2) + (j >> 1), v | (o << 16));
        }

        // ---- publish: full drain, block barrier, tid0 uncontended atomic RMW ----
        asm volatile("s_waitcnt vmcnt(0)" ::: "memory");
        __syncthreads();
        if (tid == 0) {
            __hip_atomic_fetch_add(flags + ((size_t)bt * NWS + step) * 16 + jt, 1u,
                                   __ATOMIC_RELAXED, __HIP_MEMORY_SCOPE_AGENT);
        }

        // ---- hseq stores off the critical path ----
        if (step >= SEQ0) {
#pragma unroll
            for (int r = 0; r < 4; ++r) {
                int brow = b0 + wm * 16 + qg * 4 + r;
                unsigned v = hbf[r];
                unsigned o = __shfl_xor(v, 1);
                if (!(lane & 1))
                    *(unsigned*)(hseq + ((size_t)brow * PRE + (step - SEQ0)) * H_DIM +
                                 (j & ~1)) = v | (o << 16);
            }
        }
    };

    for (int step = 0; step < NWS; step += 2) {
        STEP(step, yf0, yf1);
        STEP(step + 1, yf1, yf0);
    }
}

// ---------------------------------------------------------------------------
// fc2 as bf16 MFMA GEMM (round-13 version, proven)
// ---------------------------------------------------------------------------
__global__ void __launch_bounds__(256)
fc2_mfma(const unsigned short* __restrict__ hseq,
         const unsigned short* __restrict__ w2,
         const float* __restrict__ bias,
         float* __restrict__ out) {
    const int tid = threadIdx.x;
    const int lane = tid & 63;
    const int w = tid >> 6;
    const int wm = w & 1, wn = w >> 1;
    const int row16 = lane & 15, qg = lane >> 4;
    const int mbase = blockIdx.x * 64 + wm * 32;
    const int nbase = wn * 128;

    f32x4 acc[2][8];
#pragma unroll
    for (int mt = 0; mt < 2; ++mt)
#pragma unroll
        for (int nt = 0; nt < 8; ++nt) acc[mt][nt] = f32x4{0.f, 0.f, 0.f, 0.f};

    const unsigned short* ap = hseq + (size_t)(mbase + row16) * H_DIM + qg * 8;
    const unsigned short* bp = w2 + (size_t)(nbase + row16) * H_DIM + qg * 8;
#pragma unroll
    for (int ks = 0; ks < 16; ++ks) {
        short8 a0 = *(const short8*)(ap + ks * 32);
        short8 a1 = *(const short8*)(ap + 16 * H_DIM + ks * 32);
        short8 bfr[8];
#pragma unroll
        for (int nt = 0; nt < 8; ++nt)
            bfr[nt] = *(const short8*)(bp + (size_t)nt * 16 * H_DIM + ks * 32);
#pragma unroll
        for (int nt = 0; nt < 8; ++nt) {
            acc[0][nt] = MFMA16(a0, bfr[nt], acc[0][nt]);
            acc[1][nt] = MFMA16(a1, bfr[nt], acc[1][nt]);
        }
    }

#pragma unroll
    for (int mt = 0; mt < 2; ++mt)
#pragma unroll
        for (int nt = 0; nt < 8; ++nt)
#pragma unroll
            for (int r = 0; r < 4; ++r) {
                int row = mbase + mt * 16 + qg * 4 + r;
                int col = nbase + nt * 16 + row16;
                out[(size_t)row * I_DIM + col] = acc[mt][nt][r] + bias[col];
            }
}

__global__ void cvt_w2(const float* __restrict__ w, unsigned short* __restrict__ o, int n) {
    int i = blockIdx.x * 256 + threadIdx.x;
    if (i < n) o[i] = f2bf(w[i]);
}

extern "C" void kernel_launch(void* const* d_in, const int* in_sizes, int n_in,
                              void* d_out, int out_size, void* d_ws, size_t ws_size,
                              hipStream_t stream) {
    const float* x     = (const float*)d_in[0];
    const float* fc1_w = (const float*)d_in[1];
    const float* fc1_b = (const float*)d_in[2];
    const float* W_ih  = (const float*)d_in[3];
    const float* W_hh  = (const float*)d_in[4];
    const float* b_ih  = (const float*)d_in[5];
    const float* b_hh  = (const float*)d_in[6];
    const float* fc2_w = (const float*)d_in[7];
    const float* fc2_b = (const float*)d_in[8];
    float* out = (float*)d_out;

    unsigned short* ws = (unsigned short*)d_ws;
    unsigned short* y_bf  = ws;                       // 8388608 us
    unsigned short* h0    = ws + 8388608;             // 262144
    unsigned short* h1    = ws + 8650752;             // 262144
    unsigned short* hseq  = ws + 8912896;             // 6291456
    unsigned short* w2_bf = ws + 15204352;            // 131072
    unsigned* flags = (unsigned*)(ws + 15335424);     // 16*64*16 u32 = 64KB

    hipMemsetAsync(h0, 0, 262144 * sizeof(unsigned short), stream);
    hipMemsetAsync(flags, 0, 16 * NWS * 16 * sizeof(unsigned), stream);

    cvt_w2<<<dim3((I_DIM * H_DIM + 255) / 256), dim3(256), 0, stream>>>(
        fc2_w, w2_bf, I_DIM * H_DIM);

    fc1_kernel<<<dim3(B_DIM), dim3(256), 0, stream>>>(x, fc1_w, fc1_b, y_bf);

    hipFuncSetAttribute((const void*)gru_persist,
                        hipFuncAttributeMaxDynamicSharedMemorySize, LDSB);

    // NORMAL launch: 256 blocks @ 147KB LDS = 1 block/CU on a 256-CU chip ->
    // all blocks co-resident; spin protocol identical to the cooperative case.
    gru_persist<<<dim3(256), dim3(256), LDSB, stream>>>(
        y_bf, W_ih, b_ih, W_hh, b_hh, h0, h1, hseq, flags);

    fc2_mfma<<<dim3((B_DIM * PRE) / 64), dim3(256), 0, stream>>>(
        hseq, w2_bf, fc2_b, out);
}

// Round 15
// 549.275 us; speedup vs baseline: 1.0777x; 1.0777x over previous
//
#include <hip/hip_runtime.h>
#include <math.h>

#define B_DIM 512
#define WS_DIM 128
#define I_DIM 256
#define H_DIM 512
#define NWS 64
#define PRE 24
#define SEQ0 (NWS - PRE)  // 40

typedef __attribute__((ext_vector_type(8))) short short8;
typedef __attribute__((ext_vector_type(4))) float f32x4;

#define MFMA16(a, b, c) __builtin_amdgcn_mfma_f32_16x16x32_bf16((a), (b), (c), 0, 0, 0)

__device__ __forceinline__ unsigned short f2bf(float f) {
    unsigned u = __float_as_uint(f);
    u += 0x7FFF + ((u >> 16) & 1);
    return (unsigned short)(u >> 16);
}
__device__ __forceinline__ float bf2f(unsigned short h) {
    return __uint_as_float(((unsigned)h) << 16);
}
__device__ __forceinline__ short8 cvt8(const float* p) {
    float4 lo = *(const float4*)p;
    float4 hi = *(const float4*)(p + 4);
    short8 r;
    r[0] = (short)f2bf(lo.x); r[1] = (short)f2bf(lo.y);
    r[2] = (short)f2bf(lo.z); r[3] = (short)f2bf(lo.w);
    r[4] = (short)f2bf(hi.x); r[5] = (short)f2bf(hi.y);
    r[6] = (short)f2bf(hi.z); r[7] = (short)f2bf(hi.w);
    return r;
}

// Device-coherent (MALL) accesses: bypass the non-coherent per-XCD L2s.
__device__ __forceinline__ unsigned ld_dev(const unsigned* p) {
    return __hip_atomic_load((unsigned*)p, __ATOMIC_RELAXED, __HIP_MEMORY_SCOPE_AGENT);
}
__device__ __forceinline__ unsigned long long ld_dev64(const unsigned long long* p) {
    return __hip_atomic_load((unsigned long long*)p, __ATOMIC_RELAXED, __HIP_MEMORY_SCOPE_AGENT);
}
__device__ __forceinline__ void st_dev(unsigned* p, unsigned v) {
    __hip_atomic_store(p, v, __ATOMIC_RELAXED, __HIP_MEMORY_SCOPE_AGENT);
}

// ---------------------------------------------------------------------------
// K1: fc1 over the time axis -> y bf16. (round-13 version, proven)
// ---------------------------------------------------------------------------
__global__ void __launch_bounds__(256) fc1_kernel(const float* __restrict__ x,
                                                  const float* __restrict__ fc1_w,
                                                  const float* __restrict__ fc1_b,
                                                  unsigned short* __restrict__ y) {
    __shared__ float wsm[NWS * WS_DIM];  // 64*128 f32 = 32KB
    const int b = blockIdx.x;
    const int i = threadIdx.x;  // 0..255 == I_DIM

    for (int idx = i; idx < NWS * WS_DIM; idx += 256) wsm[idx] = fc1_w[idx];
    __syncthreads();

    float acc[NWS];
#pragma unroll
    for (int n = 0; n < NWS; ++n) acc[n] = fc1_b[n];

    const float* xb = x + (size_t)b * WS_DIM * I_DIM + i;
    for (int t = 0; t < WS_DIM; ++t) {
        float xv = xb[(size_t)t * I_DIM];
#pragma unroll
        for (int n = 0; n < NWS; ++n) acc[n] += xv * wsm[n * WS_DIM + t];
    }

    unsigned short* yb = y + (size_t)b * NWS * I_DIM + i;
#pragma unroll
    for (int n = 0; n < NWS; ++n) yb[(size_t)n * I_DIM] = f2bf(acc[n]);
}

// ---------------------------------------------------------------------------
// Persistent GRU recurrence — NORMAL launch (r14-proven), r14 sync verbatim.
// Round-15 changes: (1) hprev carried in registers across steps (same lane
// computes the same (brow,j) every step); (2) Whh in VGPRs (wh[16][3]) —
// hidden phase is register-only MFMA; (3) LDS = 48KB input weights only.
// ---------------------------------------------------------------------------
__global__ void __launch_bounds__(256, 1)
gru_persist(const unsigned short* __restrict__ y,  // [B,NWS,I] bf16
            const float* __restrict__ Wih, const float* __restrict__ bih,
            const float* __restrict__ Whh, const float* __restrict__ bhh,
            unsigned short* __restrict__ hA,   // ping [B,H] bf16 (pre-zeroed)
            unsigned short* __restrict__ hB,   // pong
            unsigned short* __restrict__ hseq, // [B,PRE,H] bf16
            unsigned* __restrict__ flags) {    // [16][NWS][16] (pre-zeroed)
    __shared__ char lds[8 * 6144];  // 48KB: input weights, swizzled
    const int tid = threadIdx.x;
    const int lane = tid & 63;
    const int w = tid >> 6;
    const int wm = w & 1;
    const int jh = w >> 1;
    const int bt = blockIdx.x & 15;
    const int jt = blockIdx.x >> 4;
    const int b0 = bt * 32;
    const int j0 = jt * 32;

    // ---- input weights (Wih) -> swizzled LDS ----
    for (int idx = tid; idx < 96 * 256; idx += 256) {
        int n = idx >> 8, k = idx & 255;
        int g = n >> 5, jj2 = n & 31;
        float wv = Wih[(size_t)(g * H_DIM + j0 + jj2) * I_DIM + k];
        int ks = k >> 5, q = (k & 31) >> 3, e = k & 7;
        int byteoff = ks * 6144 + (((n * 64 + q * 16) ^ ((n & 7) << 4)) + e * 2);
        *(unsigned short*)(lds + byteoff) = f2bf(wv);
    }

    const int row16 = lane & 15;
    const int qg = lane >> 4;
    const int bbA = b0 + wm * 16 + row16;  // A-fragment source row
    const int jj = jh * 16 + row16;        // C col within 32-j slice
    const int j = j0 + jj;

    // ---- hidden weights (Whh) -> VGPRs: wh[ks][gate], 48 x short8 ----
    short8 wh[16][3];
#pragma unroll
    for (int ks = 0; ks < 16; ++ks)
#pragma unroll
        for (int g = 0; g < 3; ++g)
            wh[ks][g] = cvt8(&Whh[(size_t)(g * H_DIM + j0 + jj) * H_DIM + ks * 32 + qg * 8]);

    const int n0r = jj, n1r = 32 + jj, n2r = 64 + jj;
    const int bof0 = (n0r * 64 + qg * 16) ^ ((n0r & 7) << 4);
    const int bof1 = (n1r * 64 + qg * 16) ^ ((n1r & 7) << 4);
    const int bof2 = (n2r * 64 + qg * 16) ^ ((n2r & 7) << 4);

    const float br_i = bih[j], br_h = bhh[j];
    const float bz_i = bih[H_DIM + j], bz_h = bhh[H_DIM + j];
    const float bn_i = bih[2 * H_DIM + j], bn_h = bhh[2 * H_DIM + j];

    __syncthreads();  // LDS weights ready (one-time)

    const unsigned short* ybase = y + (size_t)bbA * NWS * I_DIM + qg * 8;

    short8 yf0[8], yf1[8];
#pragma unroll
    for (int ks = 0; ks < 8; ++ks) yf0[ks] = *(const short8*)(ybase + ks * 32);

    // hprev register carry: this lane's epilogue rows/col are identical every
    // step, and h0 is zero-initialized.
    unsigned short hprevreg[4] = {0, 0, 0, 0};

    auto STEP = [&](int step, short8(&yc)[8], short8(&yn)[8]) {
        const unsigned short* hin = (step & 1) ? hB : hA;
        unsigned short* hout      = (step & 1) ? hA : hB;

        f32x4 aR = {br_i, br_i, br_i, br_i};
        f32x4 aZ = {bz_i, bz_i, bz_i, bz_i};
        f32x4 aN = {bn_i, bn_i, bn_i, bn_i};

        // ---- input phase (no h dependency) ----
#pragma unroll
        for (int ks = 0; ks < 8; ++ks) {
            short8 bf0 = *(const short8*)(lds + ks * 6144 + bof0);
            short8 bf1 = *(const short8*)(lds + ks * 6144 + bof1);
            short8 bf2 = *(const short8*)(lds + ks * 6144 + bof2);
            aR = MFMA16(yc[ks], bf0, aR);
            aZ = MFMA16(yc[ks], bf1, aZ);
            aN = MFMA16(yc[ks], bf2, aN);
        }

        // ---- prefetch next step's y fragments (overlaps the wait) ----
        int sn = (step + 1 < NWS) ? step + 1 : NWS - 1;
        const unsigned short* ypn = ybase + (size_t)sn * I_DIM;
#pragma unroll
        for (int ks = 0; ks < 8; ++ks) yn[ks] = *(const short8*)(ypn + ks * 32);

        // ---- wait: 16 per-block flag words for step-1, polled in parallel ----
        if (step > 0) {
            const unsigned* dw = flags + ((size_t)bt * NWS + (step - 1)) * 16;
            while (true) {
                unsigned v = ld_dev(dw + (lane & 15));
                if (__all(v != 0)) break;
                __builtin_amdgcn_s_sleep(1);
            }
            asm volatile("" ::: "memory");
            __syncthreads();
        }

        // ---- h fragment loads (MALL-coherent) ----
        const unsigned long long* hq = (const unsigned long long*)(hin + (size_t)bbA * H_DIM);
        short8 hf[16];
#pragma unroll
        for (int ks = 0; ks < 16; ++ks) {
            union { unsigned long long u[2]; short8 s; } t;
            t.u[0] = ld_dev64(hq + ks * 8 + qg * 2);
            t.u[1] = ld_dev64(hq + ks * 8 + qg * 2 + 1);
            hf[ks] = t.s;
        }

        // ---- hidden phase: B-operands from VGPRs ----
        f32x4 hR = {br_h, br_h, br_h, br_h};
        f32x4 hZ = {bz_h, bz_h, bz_h, bz_h};
        f32x4 hN = {bn_h, bn_h, bn_h, bn_h};
#pragma unroll
        for (int ks = 0; ks < 16; ++ks) {
            hR = MFMA16(hf[ks], wh[ks][0], hR);
            hZ = MFMA16(hf[ks], wh[ks][1], hZ);
            hN = MFMA16(hf[ks], wh[ks][2], hN);
        }

        // ---- epilogue: gating; C/D layout col=lane&15, row=qg*4+r ----
        unsigned short hbf[4];
#pragma unroll
        for (int r = 0; r < 4; ++r) {
            int brow = b0 + wm * 16 + qg * 4 + r;
            float pr = aR[r] + hR[r];
            float pz = aZ[r] + hZ[r];
            float rr = 1.f / (1.f + __expf(-pr));
            float zz = 1.f / (1.f + __expf(-pz));
            float pn = aN[r] + rr * hN[r];
            float ax = fabsf(pn);
            float e2 = __expf(2.f * ax);
            float nn = copysignf(1.f - 2.f / (e2 + 1.f), pn);
            float hprev = bf2f(hprevreg[r]);
            float hnew = (1.f - zz) * nn + zz * hprev;
            hbf[r] = f2bf(hnew);
            hprevreg[r] = hbf[r];
            unsigned v = hbf[r];
            unsigned o = __shfl_xor(v, 1);
            if (!(lane & 1))
                st_dev((unsigned*)hout + brow * (H_DIM / 2) + (j >> 1), v | (o << 16));
        }

        // ---- publish: full drain, block barrier, tid0 uncontended atomic RMW ----
        asm volatile("s_waitcnt vmcnt(0)" ::: "memory");
        __syncthreads();
        if (tid == 0) {
            __hip_atomic_fetch_add(flags + ((size_t)bt * NWS + step) * 16 + jt, 1u,
                                   __ATOMIC_RELAXED, __HIP_MEMORY_SCOPE_AGENT);
        }

        // ---- hseq stores off the critical path ----
        if (step >= SEQ0) {
#pragma unroll
            for (int r = 0; r < 4; ++r) {
                int brow = b0 + wm * 16 + qg * 4 + r;
                unsigned v = hbf[r];
                unsigned o = __shfl_xor(v, 1);
                if (!(lane & 1))
                    *(unsigned*)(hseq + ((size_t)brow * PRE + (step - SEQ0)) * H_DIM +
                                 (j & ~1)) = v | (o << 16);
            }
        }
    };

    for (int step = 0; step < NWS; step += 2) {
        STEP(step, yf0, yf1);
        STEP(step + 1, yf1, yf0);
    }
}

// ---------------------------------------------------------------------------
// fc2 as bf16 MFMA GEMM (round-13 version, proven)
// ---------------------------------------------------------------------------
__global__ void __launch_bounds__(256)
fc2_mfma(const unsigned short* __restrict__ hseq,
         const unsigned short* __restrict__ w2,
         const float* __restrict__ bias,
         float* __restrict__ out) {
    const int tid = threadIdx.x;
    const int lane = tid & 63;
    const int w = tid >> 6;
    const int wm = w & 1, wn = w >> 1;
    const int row16 = lane & 15, qg = lane >> 4;
    const int mbase = blockIdx.x * 64 + wm * 32;
    const int nbase = wn * 128;

    f32x4 acc[2][8];
#pragma unroll
    for (int mt = 0; mt < 2; ++mt)
#pragma unroll
        for (int nt = 0; nt < 8; ++nt) acc[mt][nt] = f32x4{0.f, 0.f, 0.f, 0.f};

    const unsigned short* ap = hseq + (size_t)(mbase + row16) * H_DIM + qg * 8;
    const unsigned short* bp = w2 + (size_t)(nbase + row16) * H_DIM + qg * 8;
#pragma unroll
    for (int ks = 0; ks < 16; ++ks) {
        short8 a0 = *(const short8*)(ap + ks * 32);
        short8 a1 = *(const short8*)(ap + 16 * H_DIM + ks * 32);
        short8 bfr[8];
#pragma unroll
        for (int nt = 0; nt < 8; ++nt)
            bfr[nt] = *(const short8*)(bp + (size_t)nt * 16 * H_DIM + ks * 32);
#pragma unroll
        for (int nt = 0; nt < 8; ++nt) {
            acc[0][nt] = MFMA16(a0, bfr[nt], acc[0][nt]);
            acc[1][nt] = MFMA16(a1, bfr[nt], acc[1][nt]);
        }
    }

#pragma unroll
    for (int mt = 0; mt < 2; ++mt)
#pragma unroll
        for (int nt = 0; nt < 8; ++nt)
#pragma unroll
            for (int r = 0; r < 4; ++r) {
                int row = mbase + mt * 16 + qg * 4 + r;
                int col = nbase + nt * 16 + row16;
                out[(size_t)row * I_DIM + col] = acc[mt][nt][r] + bias[col];
            }
}

__global__ void cvt_w2(const float* __restrict__ w, unsigned short* __restrict__ o, int n) {
    int i = blockIdx.x * 256 + threadIdx.x;
    if (i < n) o[i] = f2bf(w[i]);
}

extern "C" void kernel_launch(void* const* d_in, const int* in_sizes, int n_in,
                              void* d_out, int out_size, void* d_ws, size_t ws_size,
                              hipStream_t stream) {
    const float* x     = (const float*)d_in[0];
    const float* fc1_w = (const float*)d_in[1];
    const float* fc1_b = (const float*)d_in[2];
    const float* W_ih  = (const float*)d_in[3];
    const float* W_hh  = (const float*)d_in[4];
    const float* b_ih  = (const float*)d_in[5];
    const float* b_hh  = (const float*)d_in[6];
    const float* fc2_w = (const float*)d_in[7];
    const float* fc2_b = (const float*)d_in[8];
    float* out = (float*)d_out;

    unsigned short* ws = (unsigned short*)d_ws;
    unsigned short* y_bf  = ws;                       // 8388608 us
    unsigned short* h0    = ws + 8388608;             // 262144
    unsigned short* h1    = ws + 8650752;             // 262144
    unsigned short* hseq  = ws + 8912896;             // 6291456
    unsigned short* w2_bf = ws + 15204352;            // 131072
    unsigned* flags = (unsigned*)(ws + 15335424);     // 16*64*16 u32 = 64KB

    hipMemsetAsync(h0, 0, 262144 * sizeof(unsigned short), stream);
    hipMemsetAsync(flags, 0, 16 * NWS * 16 * sizeof(unsigned), stream);

    cvt_w2<<<dim3((I_DIM * H_DIM + 255) / 256), dim3(256), 0, stream>>>(
        fc2_w, w2_bf, I_DIM * H_DIM);

    fc1_kernel<<<dim3(B_DIM), dim3(256), 0, stream>>>(x, fc1_w, fc1_b, y_bf);

    // NORMAL launch (proven r14): 256 blocks @ 1/CU, all co-resident.
    gru_persist<<<dim3(256), dim3(256), 0, stream>>>(
        y_bf, W_ih, b_ih, W_hh, b_hh, h0, h1, hseq, flags);

    fc2_mfma<<<dim3((B_DIM * PRE) / 64), dim3(256), 0, stream>>>(
        hseq, w2_bf, fc2_b, out);
}